// Round 1
// baseline (614.788 us; speedup 1.0000x reference)
//
#include <hip/hip_runtime.h>
#include <math.h>
#include <float.h>

#define N_NODES 50000
#define N_EDGES 800000
#define DH 128

// ---------------- CSR build ----------------
__global__ void hist_kernel(const int* __restrict__ dst, int* __restrict__ counts) {
  int e = blockIdx.x * 256 + threadIdx.x;
  if (e < N_EDGES) atomicAdd(&counts[dst[e]], 1);
}

__global__ __launch_bounds__(1024) void scan_kernel(const int* __restrict__ counts,
                                                    int* __restrict__ row_ptr,
                                                    int* __restrict__ cursor) {
  const int CH = 49;  // 49*1024 = 50176 >= 50001
  int t = threadIdx.x;
  int start = t * CH;
  int total = 0;
  for (int i = 0; i < CH; ++i) {
    int idx = start + i;
    if (idx < N_NODES) total += counts[idx];
  }
  __shared__ int s[1024];
  s[t] = total;
  __syncthreads();
  for (int off = 1; off < 1024; off <<= 1) {
    int v = (t >= off) ? s[t - off] : 0;
    __syncthreads();
    s[t] += v;
    __syncthreads();
  }
  int run = s[t] - total;  // exclusive prefix of this thread's chunk
  for (int i = 0; i < CH; ++i) {
    int idx = start + i;
    if (idx < N_NODES) {
      row_ptr[idx] = run;
      cursor[idx] = run;
      run += counts[idx];
    } else if (idx == N_NODES) {
      row_ptr[N_NODES] = run;
    }
  }
}

__global__ void fill_kernel(const int* __restrict__ src, const int* __restrict__ dst,
                            int* __restrict__ cursor, int* __restrict__ elist) {
  int e = blockIdx.x * 256 + threadIdx.x;
  if (e < N_EDGES) {
    int p = atomicAdd(&cursor[dst[e]], 1);
    elist[p] = src[e];
  }
}

// ---------------- scatter-max as CSR gather: one wave per node ----------------
__global__ __launch_bounds__(256) void agg_max_kernel(const float* __restrict__ feat,
                                                      const int* __restrict__ row_ptr,
                                                      const int* __restrict__ elist,
                                                      float* __restrict__ out) {
  int node = blockIdx.x * 4 + (threadIdx.x >> 6);  // grid = 12500 -> exactly 50000
  int lane = threadIdx.x & 63;
  int e0 = row_ptr[node];
  int e1 = row_ptr[node + 1];
  float mx = -FLT_MAX, my = -FLT_MAX;
  for (int e = e0; e < e1; ++e) {
    int s = elist[e];
    const float2 v = *(const float2*)(feat + (size_t)s * DH + lane * 2);
    mx = fmaxf(mx, v.x);
    my = fmaxf(my, v.y);
  }
  if (e0 == e1) { mx = 0.f; my = 0.f; }  // isolated node -> 0 (PyG convention)
  float2 o; o.x = mx; o.y = my;
  *(float2*)(out + (size_t)node * DH + lane * 2) = o;
}

// ---------------- fused concat-GEMM: out = [Aa|Ab] @ [Wl;Wr]^T + bias ----------------
// K = 256 (128 from Aa, 128 from Ab). Tile: 128 rows x 32 cols. 256 threads, 4x4/thread.
#define RT 128
#define JT 32
#define AP 132  // padded LDS row stride (k-major A chunk), keeps b128 reads conflict-free

__global__ __launch_bounds__(256) void gemm_concat(
    const float* __restrict__ Aa, const float* __restrict__ Ab,
    const float* __restrict__ Wl, const float* __restrict__ Wr,
    const float* __restrict__ bias, float* __restrict__ out,
    int N, int ldo) {
  __shared__ float Wlds[256 * JT];   // [k][j], 32 KB
  __shared__ float Alds[32 * AP];    // [k][r] chunk, 16.5 KB
  const int tid = threadIdx.x;
  const int jbase = blockIdx.y * JT;
  const int rowBase = blockIdx.x * RT;

  // load W tile (once per block): Wlds[k*JT + jj] = W2[jbase+jj][k]
  for (int idx = tid; idx < 256 * JT; idx += 256) {
    int jj = idx & (JT - 1);
    int k = idx >> 5;
    float w = (k < 128) ? Wl[(size_t)(jbase + jj) * 128 + k]
                        : Wr[(size_t)(jbase + jj) * 128 + (k - 128)];
    Wlds[k * JT + jj] = w;
  }

  const int tx = tid & 7;   // j-group: cols jbase + tx*4 .. +3
  const int ty = tid >> 3;  // row-group: rows rowBase + ty*4 .. +3
  float acc[4][4] = {};

  for (int kc = 0; kc < 8; ++kc) {
    const float* __restrict__ srcp = (kc < 4) ? Aa : Ab;
    const int kofs = (kc & 3) * 32;
    __syncthreads();  // prior compute done (and W load done for kc==0)
    // stage A chunk transposed into LDS: 32 k x 128 r
#pragma unroll
    for (int v = 0; v < 4; ++v) {
      int fid = tid + v * 256;     // 0..1023 float4 ids
      int r = fid >> 3;            // 8 float4 per row
      int kq = (fid & 7) << 2;
      int n = rowBase + r;
      if (n >= N) n = N - 1;       // safe clamp; stores are guarded
      float4 d = *(const float4*)(srcp + (size_t)n * 128 + kofs + kq);
      Alds[(kq + 0) * AP + r] = d.x;
      Alds[(kq + 1) * AP + r] = d.y;
      Alds[(kq + 2) * AP + r] = d.z;
      Alds[(kq + 3) * AP + r] = d.w;
    }
    __syncthreads();
    const int kb = kc * 32;
#pragma unroll
    for (int kk = 0; kk < 32; ++kk) {
      float4 w = *(const float4*)&Wlds[(kb + kk) * JT + tx * 4];
      float4 a = *(const float4*)&Alds[kk * AP + ty * 4];
      acc[0][0] += a.x * w.x; acc[0][1] += a.x * w.y; acc[0][2] += a.x * w.z; acc[0][3] += a.x * w.w;
      acc[1][0] += a.y * w.x; acc[1][1] += a.y * w.y; acc[1][2] += a.y * w.z; acc[1][3] += a.y * w.w;
      acc[2][0] += a.z * w.x; acc[2][1] += a.z * w.y; acc[2][2] += a.z * w.z; acc[2][3] += a.z * w.w;
      acc[3][0] += a.w * w.x; acc[3][1] += a.w * w.y; acc[3][2] += a.w * w.z; acc[3][3] += a.w * w.w;
    }
  }

  float4 b4 = *(const float4*)(bias + jbase + tx * 4);
#pragma unroll
  for (int i = 0; i < 4; ++i) {
    int n = rowBase + ty * 4 + i;
    if (n < N) {
      float4 o;
      o.x = acc[i][0] + b4.x;
      o.y = acc[i][1] + b4.y;
      o.z = acc[i][2] + b4.z;
      o.w = acc[i][3] + b4.w;
      *(float4*)(out + (size_t)n * ldo + jbase + tx * 4) = o;
    }
  }
}

// ---------------- batch-norm ----------------
__global__ __launch_bounds__(256) void bn_stats_kernel(const float* __restrict__ h,
                                                       float* __restrict__ sums) {
  int j = threadIdx.x & 127;
  int rh = threadIdx.x >> 7;
  float s = 0.f, sq = 0.f;
  for (int n = blockIdx.x * 2 + rh; n < N_NODES; n += gridDim.x * 2) {
    float v = h[(size_t)n * DH + j];
    s += v;
    sq += v * v;
  }
  __shared__ float ls[256], lq[256];
  ls[threadIdx.x] = s;
  lq[threadIdx.x] = sq;
  __syncthreads();
  if (rh == 0) {
    atomicAdd(&sums[j], ls[j] + ls[j + 128]);
    atomicAdd(&sums[128 + j], lq[j] + lq[j + 128]);
  }
}

__global__ __launch_bounds__(256) void bn_apply_kernel(float* __restrict__ h,
                                                       const float* __restrict__ sums,
                                                       const float* __restrict__ gamma,
                                                       const float* __restrict__ beta) {
  int i4 = (blockIdx.x * 256 + threadIdx.x) * 4;
  if (i4 >= N_NODES * DH) return;
  int j = i4 & 127;
  float4 v = *(const float4*)(h + i4);
  float* vv = (float*)&v;
  const float inv = 1.f / (float)N_NODES;
#pragma unroll
  for (int c = 0; c < 4; ++c) {
    float mean = sums[j + c] * inv;
    float var = sums[128 + j + c] * inv - mean * mean;
    float x = (vv[c] - mean) * rsqrtf(var + 1e-5f) * gamma[j + c] + beta[j + c];
    vv[c] = fmaxf(x, 0.f);
  }
  *(float4*)(h + i4) = v;
}

// ---------------- launcher ----------------
extern "C" void kernel_launch(void* const* d_in, const int* in_sizes, int n_in,
                              void* d_out, int out_size, void* d_ws, size_t ws_size,
                              hipStream_t stream) {
  (void)in_sizes; (void)n_in; (void)out_size; (void)ws_size;
  const float* x     = (const float*)d_in[0];
  const int*   eidx  = (const int*)d_in[1];
  const float* W_l1  = (const float*)d_in[2];
  const float* b_l1  = (const float*)d_in[3];
  const float* W_r1  = (const float*)d_in[4];
  const float* gamma = (const float*)d_in[5];
  const float* beta  = (const float*)d_in[6];
  const float* W_l2  = (const float*)d_in[7];
  const float* b_l2  = (const float*)d_in[8];
  const float* W_r2  = (const float*)d_in[9];
  const int* srcp = eidx;
  const int* dstp = eidx + N_EDGES;
  float* out = (float*)d_out;

  // workspace layout (4-byte words, 16B-aligned sections)
  int* wsi = (int*)d_ws;
  int*   counts  = wsi;                        // 50000 ints
  float* sums    = (float*)(wsi + 50000);      // 256 floats (sum | sumsq)
  int*   row_ptr = wsi + 50304;                // 50001 ints
  int*   cursor  = wsi + 100308;               // 50000 ints
  int*   elist   = wsi + 150308;               // 800000 ints
  float* aggbuf  = (float*)(wsi + 950308);     // 50000*128 floats
  float* hbuf    = (float*)(wsi + 7350308);    // 50000*128 floats
  // total = 13,750,308 words ~= 52.5 MiB

  hipMemsetAsync(d_ws, 0, (size_t)50256 * 4, stream);  // counts + bn sums

  hist_kernel<<<dim3((N_EDGES + 255) / 256), 256, 0, stream>>>(dstp, counts);
  scan_kernel<<<dim3(1), 1024, 0, stream>>>(counts, row_ptr, cursor);
  fill_kernel<<<dim3((N_EDGES + 255) / 256), 256, 0, stream>>>(srcp, dstp, cursor, elist);

  // layer 1
  agg_max_kernel<<<dim3(N_NODES / 4), 256, 0, stream>>>(x, row_ptr, elist, aggbuf);
  gemm_concat<<<dim3(391, 4), 256, 0, stream>>>(aggbuf, x, W_l1, W_r1, b_l1, hbuf, N_NODES, 128);
  bn_stats_kernel<<<dim3(500), 256, 0, stream>>>(hbuf, sums);
  bn_apply_kernel<<<dim3(6250), 256, 0, stream>>>(hbuf, sums, gamma, beta);

  // layer 2
  agg_max_kernel<<<dim3(N_NODES / 4), 256, 0, stream>>>(hbuf, row_ptr, elist, aggbuf);
  gemm_concat<<<dim3(391, 1), 256, 0, stream>>>(aggbuf, hbuf, W_l2, W_r2, b_l2, out, N_NODES, 32);
}

// Round 2
// 493.382 us; speedup vs baseline: 1.2461x; 1.2461x over previous
//
#include <hip/hip_runtime.h>
#include <math.h>
#include <float.h>

#define N_NODES 50000
#define N_EDGES 800000
#define DH 128
#define NBLK_SCAN 196  // 196*256 = 50176 >= 50001

// ---------------- CSR build ----------------
__global__ void hist_kernel(const int* __restrict__ dst, int* __restrict__ counts) {
  int e = blockIdx.x * 256 + threadIdx.x;
  if (e < N_EDGES) atomicAdd(&counts[dst[e]], 1);
}

// phase 1: per-block sums of counts (coalesced)
__global__ __launch_bounds__(256) void block_sum_kernel(const int* __restrict__ counts,
                                                        int* __restrict__ blocksums) {
  int t = threadIdx.x;
  int idx = blockIdx.x * 256 + t;
  int v = (idx < N_NODES) ? counts[idx] : 0;
  __shared__ int s[256];
  s[t] = v;
  __syncthreads();
  for (int off = 128; off > 0; off >>= 1) {
    if (t < off) s[t] += s[t + off];
    __syncthreads();
  }
  if (t == 0) blocksums[blockIdx.x] = s[0];
}

// phase 2: each block scans the tiny blocksums array + its own 256 counts (coalesced)
__global__ __launch_bounds__(256) void scan_fill_kernel(const int* __restrict__ counts,
                                                        const int* __restrict__ blocksums,
                                                        int* __restrict__ row_ptr,
                                                        int* __restrict__ cursor) {
  __shared__ int s[256];
  int t = threadIdx.x;
  // inclusive scan of blocksums (196 entries, redundant per block — tiny)
  s[t] = (t < NBLK_SCAN) ? blocksums[t] : 0;
  __syncthreads();
  for (int off = 1; off < 256; off <<= 1) {
    int v = (t >= off) ? s[t - off] : 0;
    __syncthreads();
    s[t] += v;
    __syncthreads();
  }
  int base = (blockIdx.x == 0) ? 0 : s[blockIdx.x - 1];
  __syncthreads();
  // inclusive scan of this block's counts
  int idx = blockIdx.x * 256 + t;
  int c = (idx < N_NODES) ? counts[idx] : 0;
  s[t] = c;
  __syncthreads();
  for (int off = 1; off < 256; off <<= 1) {
    int v = (t >= off) ? s[t - off] : 0;
    __syncthreads();
    s[t] += v;
    __syncthreads();
  }
  int rp = base + s[t] - c;  // exclusive prefix
  if (idx < N_NODES) { row_ptr[idx] = rp; cursor[idx] = rp; }
  if (idx == N_NODES) row_ptr[N_NODES] = rp;  // == 800000
}

__global__ void fill_kernel(const int* __restrict__ src, const int* __restrict__ dst,
                            int* __restrict__ cursor, int* __restrict__ elist) {
  int e = blockIdx.x * 256 + threadIdx.x;
  if (e < N_EDGES) {
    int p = atomicAdd(&cursor[dst[e]], 1);
    elist[p] = src[e];
  }
}

// ---------------- scatter-max as CSR gather: one wave per node ----------------
__global__ __launch_bounds__(256) void agg_max_kernel(const float* __restrict__ feat,
                                                      const int* __restrict__ row_ptr,
                                                      const int* __restrict__ elist,
                                                      float* __restrict__ out) {
  int node = blockIdx.x * 4 + (threadIdx.x >> 6);  // grid = 12500 -> exactly 50000
  int lane = threadIdx.x & 63;
  int e0 = row_ptr[node];
  int e1 = row_ptr[node + 1];
  float mx = -FLT_MAX, my = -FLT_MAX;
  for (int e = e0; e < e1; ++e) {
    int s = elist[e];
    const float2 v = *(const float2*)(feat + (size_t)s * DH + lane * 2);
    mx = fmaxf(mx, v.x);
    my = fmaxf(my, v.y);
  }
  if (e0 == e1) { mx = 0.f; my = 0.f; }  // isolated node -> 0 (PyG convention)
  float2 o; o.x = mx; o.y = my;
  *(float2*)(out + (size_t)node * DH + lane * 2) = o;
}

// ---------------- fused concat-GEMM: out = [Aa|Ab] @ [Wl;Wr]^T + bias ----------------
// K = 256 (128 from Aa, 128 from Ab). Tile: 128 rows x 32 cols. 256 threads, 4x4/thread.
#define RT 128
#define JT 32
#define AP 132  // padded LDS row stride (k-major A chunk), keeps b128 reads conflict-free

__global__ __launch_bounds__(256) void gemm_concat(
    const float* __restrict__ Aa, const float* __restrict__ Ab,
    const float* __restrict__ Wl, const float* __restrict__ Wr,
    const float* __restrict__ bias, float* __restrict__ out,
    int N, int ldo) {
  __shared__ float Wlds[256 * JT];   // [k][j], 32 KB
  __shared__ float Alds[32 * AP];    // [k][r] chunk, 16.5 KB
  const int tid = threadIdx.x;
  const int jbase = blockIdx.y * JT;
  const int rowBase = blockIdx.x * RT;

  // load W tile (once per block): Wlds[k*JT + jj] = W2[jbase+jj][k]
  for (int idx = tid; idx < 256 * JT; idx += 256) {
    int jj = idx & (JT - 1);
    int k = idx >> 5;
    float w = (k < 128) ? Wl[(size_t)(jbase + jj) * 128 + k]
                        : Wr[(size_t)(jbase + jj) * 128 + (k - 128)];
    Wlds[k * JT + jj] = w;
  }

  const int tx = tid & 7;   // j-group: cols jbase + tx*4 .. +3
  const int ty = tid >> 3;  // row-group: rows rowBase + ty*4 .. +3
  float acc[4][4] = {};

  for (int kc = 0; kc < 8; ++kc) {
    const float* __restrict__ srcp = (kc < 4) ? Aa : Ab;
    const int kofs = (kc & 3) * 32;
    __syncthreads();  // prior compute done (and W load done for kc==0)
    // stage A chunk transposed into LDS: 32 k x 128 r
#pragma unroll
    for (int v = 0; v < 4; ++v) {
      int fid = tid + v * 256;     // 0..1023 float4 ids
      int r = fid >> 3;            // 8 float4 per row
      int kq = (fid & 7) << 2;
      int n = rowBase + r;
      if (n >= N) n = N - 1;       // safe clamp; stores are guarded
      float4 d = *(const float4*)(srcp + (size_t)n * 128 + kofs + kq);
      Alds[(kq + 0) * AP + r] = d.x;
      Alds[(kq + 1) * AP + r] = d.y;
      Alds[(kq + 2) * AP + r] = d.z;
      Alds[(kq + 3) * AP + r] = d.w;
    }
    __syncthreads();
    const int kb = kc * 32;
#pragma unroll
    for (int kk = 0; kk < 32; ++kk) {
      float4 w = *(const float4*)&Wlds[(kb + kk) * JT + tx * 4];
      float4 a = *(const float4*)&Alds[kk * AP + ty * 4];
      acc[0][0] += a.x * w.x; acc[0][1] += a.x * w.y; acc[0][2] += a.x * w.z; acc[0][3] += a.x * w.w;
      acc[1][0] += a.y * w.x; acc[1][1] += a.y * w.y; acc[1][2] += a.y * w.z; acc[1][3] += a.y * w.w;
      acc[2][0] += a.z * w.x; acc[2][1] += a.z * w.y; acc[2][2] += a.z * w.z; acc[2][3] += a.z * w.w;
      acc[3][0] += a.w * w.x; acc[3][1] += a.w * w.y; acc[3][2] += a.w * w.z; acc[3][3] += a.w * w.w;
    }
  }

  float4 b4 = *(const float4*)(bias + jbase + tx * 4);
#pragma unroll
  for (int i = 0; i < 4; ++i) {
    int n = rowBase + ty * 4 + i;
    if (n < N) {
      float4 o;
      o.x = acc[i][0] + b4.x;
      o.y = acc[i][1] + b4.y;
      o.z = acc[i][2] + b4.z;
      o.w = acc[i][3] + b4.w;
      *(float4*)(out + (size_t)n * ldo + jbase + tx * 4) = o;
    }
  }
}

// ---------------- batch-norm ----------------
__global__ __launch_bounds__(256) void bn_stats_kernel(const float* __restrict__ h,
                                                       float* __restrict__ sums) {
  int j = threadIdx.x & 127;
  int rh = threadIdx.x >> 7;
  float s = 0.f, sq = 0.f;
  for (int n = blockIdx.x * 2 + rh; n < N_NODES; n += gridDim.x * 2) {
    float v = h[(size_t)n * DH + j];
    s += v;
    sq += v * v;
  }
  __shared__ float ls[256], lq[256];
  ls[threadIdx.x] = s;
  lq[threadIdx.x] = sq;
  __syncthreads();
  if (rh == 0) {
    atomicAdd(&sums[j], ls[j] + ls[j + 128]);
    atomicAdd(&sums[128 + j], lq[j] + lq[j + 128]);
  }
}

__global__ __launch_bounds__(256) void bn_apply_kernel(float* __restrict__ h,
                                                       const float* __restrict__ sums,
                                                       const float* __restrict__ gamma,
                                                       const float* __restrict__ beta) {
  int i4 = (blockIdx.x * 256 + threadIdx.x) * 4;
  if (i4 >= N_NODES * DH) return;
  int j = i4 & 127;
  float4 v = *(const float4*)(h + i4);
  float* vv = (float*)&v;
  const float inv = 1.f / (float)N_NODES;
#pragma unroll
  for (int c = 0; c < 4; ++c) {
    float mean = sums[j + c] * inv;
    float var = sums[128 + j + c] * inv - mean * mean;
    float x = (vv[c] - mean) * rsqrtf(var + 1e-5f) * gamma[j + c] + beta[j + c];
    vv[c] = fmaxf(x, 0.f);
  }
  *(float4*)(h + i4) = v;
}

// ---------------- launcher ----------------
extern "C" void kernel_launch(void* const* d_in, const int* in_sizes, int n_in,
                              void* d_out, int out_size, void* d_ws, size_t ws_size,
                              hipStream_t stream) {
  (void)in_sizes; (void)n_in; (void)out_size; (void)ws_size;
  const float* x     = (const float*)d_in[0];
  const int*   eidx  = (const int*)d_in[1];
  const float* W_l1  = (const float*)d_in[2];
  const float* b_l1  = (const float*)d_in[3];
  const float* W_r1  = (const float*)d_in[4];
  const float* gamma = (const float*)d_in[5];
  const float* beta  = (const float*)d_in[6];
  const float* W_l2  = (const float*)d_in[7];
  const float* b_l2  = (const float*)d_in[8];
  const float* W_r2  = (const float*)d_in[9];
  const int* srcp = eidx;
  const int* dstp = eidx + N_EDGES;
  float* out = (float*)d_out;

  // workspace layout (4-byte words, 16B-aligned sections)
  int* wsi = (int*)d_ws;
  int*   counts  = wsi;                        // 50000 ints
  float* sums    = (float*)(wsi + 50000);      // 256 floats (sum | sumsq)
  int*   row_ptr = wsi + 50304;                // 50001 ints
  int*   cursor  = wsi + 100308;               // 50000 ints
  int*   elist   = wsi + 150308;               // 800000 ints
  float* aggbuf  = (float*)(wsi + 950308);     // 50000*128 floats
  float* hbuf    = (float*)(wsi + 7350308);    // 50000*128 floats
  int*   blocksums = wsi + 13750308;           // 196 ints
  // total ~= 52.5 MiB

  hipMemsetAsync(d_ws, 0, (size_t)50256 * 4, stream);  // counts + bn sums

  hist_kernel<<<dim3((N_EDGES + 255) / 256), 256, 0, stream>>>(dstp, counts);
  block_sum_kernel<<<dim3(NBLK_SCAN), 256, 0, stream>>>(counts, blocksums);
  scan_fill_kernel<<<dim3(NBLK_SCAN), 256, 0, stream>>>(counts, blocksums, row_ptr, cursor);
  fill_kernel<<<dim3((N_EDGES + 255) / 256), 256, 0, stream>>>(srcp, dstp, cursor, elist);

  // layer 1
  agg_max_kernel<<<dim3(N_NODES / 4), 256, 0, stream>>>(x, row_ptr, elist, aggbuf);
  gemm_concat<<<dim3(391, 4), 256, 0, stream>>>(aggbuf, x, W_l1, W_r1, b_l1, hbuf, N_NODES, 128);
  bn_stats_kernel<<<dim3(500), 256, 0, stream>>>(hbuf, sums);
  bn_apply_kernel<<<dim3(6250), 256, 0, stream>>>(hbuf, sums, gamma, beta);

  // layer 2
  agg_max_kernel<<<dim3(N_NODES / 4), 256, 0, stream>>>(hbuf, row_ptr, elist, aggbuf);
  gemm_concat<<<dim3(391, 1), 256, 0, stream>>>(aggbuf, hbuf, W_l2, W_r2, b_l2, out, N_NODES, 32);
}

// Round 3
// 418.415 us; speedup vs baseline: 1.4693x; 1.1792x over previous
//
#include <hip/hip_runtime.h>
#include <math.h>
#include <float.h>

#define N_NODES 50000
#define N_EDGES 800000
#define DH 128
#define NBLK_SCAN 196  // 196*256 = 50176 >= 50001

typedef __attribute__((ext_vector_type(8))) short bf16x8;
typedef __attribute__((ext_vector_type(4))) float f32x4;

static __device__ __forceinline__ unsigned short f2bf(float f) {
  unsigned int u = __float_as_uint(f);
  u = (u + 0x7fff + ((u >> 16) & 1)) >> 16;  // RNE
  return (unsigned short)u;
}

// ---------------- CSR build ----------------
__global__ void hist_kernel(const int* __restrict__ dst, int* __restrict__ counts) {
  int e = blockIdx.x * 256 + threadIdx.x;
  if (e < N_EDGES) atomicAdd(&counts[dst[e]], 1);
}

__global__ __launch_bounds__(256) void block_sum_kernel(const int* __restrict__ counts,
                                                        int* __restrict__ blocksums) {
  int t = threadIdx.x;
  int idx = blockIdx.x * 256 + t;
  int v = (idx < N_NODES) ? counts[idx] : 0;
  __shared__ int s[256];
  s[t] = v;
  __syncthreads();
  for (int off = 128; off > 0; off >>= 1) {
    if (t < off) s[t] += s[t + off];
    __syncthreads();
  }
  if (t == 0) blocksums[blockIdx.x] = s[0];
}

__global__ __launch_bounds__(256) void scan_fill_kernel(const int* __restrict__ counts,
                                                        const int* __restrict__ blocksums,
                                                        int* __restrict__ row_ptr,
                                                        int* __restrict__ cursor) {
  __shared__ int s[256];
  int t = threadIdx.x;
  s[t] = (t < NBLK_SCAN) ? blocksums[t] : 0;
  __syncthreads();
  for (int off = 1; off < 256; off <<= 1) {
    int v = (t >= off) ? s[t - off] : 0;
    __syncthreads();
    s[t] += v;
    __syncthreads();
  }
  int base = (blockIdx.x == 0) ? 0 : s[blockIdx.x - 1];
  __syncthreads();
  int idx = blockIdx.x * 256 + t;
  int c = (idx < N_NODES) ? counts[idx] : 0;
  s[t] = c;
  __syncthreads();
  for (int off = 1; off < 256; off <<= 1) {
    int v = (t >= off) ? s[t - off] : 0;
    __syncthreads();
    s[t] += v;
    __syncthreads();
  }
  int rp = base + s[t] - c;
  if (idx < N_NODES) { row_ptr[idx] = rp; cursor[idx] = rp; }
  if (idx == N_NODES) row_ptr[N_NODES] = rp;
}

__global__ void fill_kernel(const int* __restrict__ src, const int* __restrict__ dst,
                            int* __restrict__ cursor, int* __restrict__ elist) {
  int e = blockIdx.x * 256 + threadIdx.x;
  if (e < N_EDGES) {
    int p = atomicAdd(&cursor[dst[e]], 1);
    elist[p] = src[e];
  }
}

// ---------------- conversions ----------------
// 4 floats -> 2 packed uints per thread
__global__ __launch_bounds__(256) void to_bf16_kernel(const float* __restrict__ in,
                                                      unsigned int* __restrict__ out, int n4) {
  int i = blockIdx.x * 256 + threadIdx.x;
  if (i >= n4) return;
  float4 v = ((const float4*)in)[i];
  uint2 o;
  o.x = (unsigned int)f2bf(v.x) | ((unsigned int)f2bf(v.y) << 16);
  o.y = (unsigned int)f2bf(v.z) | ((unsigned int)f2bf(v.w) << 16);
  ((uint2*)out)[i] = o;
}

// Wcat1[128][256] = [Wl1 | Wr1] rows; Wcat2[32][256] = [Wl2 | Wr2] rows (bf16)
__global__ __launch_bounds__(256) void convert_weights(
    const float* __restrict__ Wl1, const float* __restrict__ Wr1,
    const float* __restrict__ Wl2, const float* __restrict__ Wr2,
    unsigned short* __restrict__ Wcat1, unsigned short* __restrict__ Wcat2) {
  int i = blockIdx.x * 256 + threadIdx.x;  // 160*256 = 40960 total
  if (i < 32768) {
    int n = i >> 8, k = i & 255;
    float w = (k < 128) ? Wl1[n * 128 + k] : Wr1[n * 128 + (k - 128)];
    Wcat1[i] = f2bf(w);
  } else if (i < 40960) {
    int j = i - 32768;
    int n = j >> 8, k = j & 255;
    float w = (k < 128) ? Wl2[n * 128 + k] : Wr2[n * 128 + (k - 128)];
    Wcat2[j] = f2bf(w);
  }
}

// ---------------- CSR gather-max on packed bf16: one wave per node ----------------
__global__ __launch_bounds__(256) void agg_max_bf16(const unsigned int* __restrict__ feat,
                                                    const int* __restrict__ row_ptr,
                                                    const int* __restrict__ elist,
                                                    unsigned int* __restrict__ out) {
  int node = blockIdx.x * 4 + (threadIdx.x >> 6);
  int lane = threadIdx.x & 63;
  int e0 = row_ptr[node];
  int e1 = row_ptr[node + 1];
  float ma = -FLT_MAX, mb = -FLT_MAX;
  for (int e = e0; e < e1; ++e) {
    int s = elist[e];
    unsigned int v = feat[(size_t)s * 64 + lane];
    float a = __uint_as_float(v << 16);
    float b = __uint_as_float(v & 0xffff0000u);
    ma = fmaxf(ma, a);
    mb = fmaxf(mb, b);
  }
  if (e0 == e1) { ma = 0.f; mb = 0.f; }
  // inputs are bf16-exact -> truncation is exact
  unsigned int o = (__float_as_uint(ma) >> 16) | (__float_as_uint(mb) & 0xffff0000u);
  out[(size_t)node * 64 + lane] = o;
}

// ---------------- MFMA GEMM: out = [Aa|Ab](bf16) @ Wcat^T + bias ----------------
// Block: 256 thr (4 waves), tile M=128, N = NT*16, K=256. A-tile in LDS (padded),
// B fragments from L2-resident bf16 W. Verified layouts: A[m=lane&15][k=quad*8+j],
// B[n=lane&15][k=quad*8+j] (W row-major [out][in]), D col=lane&15 row=quad*4+reg.
#define ASTR 264  // 256+8 bf16 pad: dword row stride 132 % 32 = 4 -> 2-way (free)

template <int NT, bool BF16OUT>
__global__ __launch_bounds__(256) void gemm_mfma(
    const unsigned short* __restrict__ Aa, const unsigned short* __restrict__ Ab,
    const unsigned short* __restrict__ Wcat, const float* __restrict__ bias,
    unsigned short* __restrict__ outb, float* __restrict__ outf, int N) {
  __shared__ unsigned short Alds[128 * ASTR];  // 67.6 KB
  const int tid = threadIdx.x;
  const int rowBase = blockIdx.x * 128;

  // stage A tile: 128 rows x 256 k (bf16), 16B per load
#pragma unroll
  for (int it = 0; it < 16; ++it) {
    int f = tid + it * 256;        // 0..4095
    int r = f >> 5;
    int seg = f & 31;              // 32 x 16B per row
    int n = rowBase + r;
    if (n >= N) n = N - 1;
    const unsigned short* src = (seg < 16)
        ? (Aa + (size_t)n * 128 + seg * 8)
        : (Ab + (size_t)n * 128 + (seg - 16) * 8);
    int4 d = *(const int4*)src;
    *(int4*)(&Alds[r * ASTR + seg * 8]) = d;
  }
  __syncthreads();

  const int wv = tid >> 6;
  const int lane = tid & 63;
  const int ln15 = lane & 15;
  const int quad = lane >> 4;
  const int m0 = wv * 32;  // wave covers rows m0..m0+31

  f32x4 acc[2][NT] = {};

#pragma unroll
  for (int ks = 0; ks < 8; ++ks) {
    const int k0 = ks * 32;
    bf16x8 a0 = *(const bf16x8*)(&Alds[(m0 + ln15) * ASTR + k0 + quad * 8]);
    bf16x8 a1 = *(const bf16x8*)(&Alds[(m0 + 16 + ln15) * ASTR + k0 + quad * 8]);
#pragma unroll
    for (int nt = 0; nt < NT; ++nt) {
      bf16x8 b = *(const bf16x8*)(Wcat + (size_t)(nt * 16 + ln15) * 256 + k0 + quad * 8);
      acc[0][nt] = __builtin_amdgcn_mfma_f32_16x16x32_bf16(a0, b, acc[0][nt], 0, 0, 0);
      acc[1][nt] = __builtin_amdgcn_mfma_f32_16x16x32_bf16(a1, b, acc[1][nt], 0, 0, 0);
    }
  }

  const int ldo = NT * 16;
#pragma unroll
  for (int mt = 0; mt < 2; ++mt) {
#pragma unroll
    for (int nt = 0; nt < NT; ++nt) {
      int col = nt * 16 + ln15;
      float bv = bias[col];
#pragma unroll
      for (int i = 0; i < 4; ++i) {
        int r = rowBase + m0 + mt * 16 + quad * 4 + i;
        if (r < N) {
          float val = acc[mt][nt][i] + bv;
          if (BF16OUT)
            outb[(size_t)r * ldo + col] = f2bf(val);
          else
            outf[(size_t)r * ldo + col] = val;
        }
      }
    }
  }
}

// ---------------- batch-norm on packed bf16 h ----------------
__global__ __launch_bounds__(256) void bn_stats_kernel(const unsigned int* __restrict__ h,
                                                       float* __restrict__ sums) {
  int j2 = threadIdx.x & 63;   // uint index -> cols 2*j2, 2*j2+1
  int rg = threadIdx.x >> 6;
  float sa = 0.f, qa = 0.f, sb = 0.f, qb = 0.f;
  for (int n = blockIdx.x * 4 + rg; n < N_NODES; n += gridDim.x * 4) {
    unsigned int v = h[(size_t)n * 64 + j2];
    float a = __uint_as_float(v << 16);
    float b = __uint_as_float(v & 0xffff0000u);
    sa += a; qa += a * a; sb += b; qb += b * b;
  }
  __shared__ float r0[256], r1[256], r2[256], r3[256];
  r0[threadIdx.x] = sa; r1[threadIdx.x] = qa;
  r2[threadIdx.x] = sb; r3[threadIdx.x] = qb;
  __syncthreads();
  if (threadIdx.x < 64) {
    int t = threadIdx.x;
    float SA = r0[t] + r0[t + 64] + r0[t + 128] + r0[t + 192];
    float QA = r1[t] + r1[t + 64] + r1[t + 128] + r1[t + 192];
    float SB = r2[t] + r2[t + 64] + r2[t + 128] + r2[t + 192];
    float QB = r3[t] + r3[t + 64] + r3[t + 128] + r3[t + 192];
    atomicAdd(&sums[2 * t], SA);
    atomicAdd(&sums[2 * t + 1], SB);
    atomicAdd(&sums[128 + 2 * t], QA);
    atomicAdd(&sums[128 + 2 * t + 1], QB);
  }
}

__global__ __launch_bounds__(256) void bn_apply_kernel(unsigned int* __restrict__ h,
                                                       const float* __restrict__ sums,
                                                       const float* __restrict__ gamma,
                                                       const float* __restrict__ beta) {
  int i = blockIdx.x * 256 + threadIdx.x;  // uint index over 3.2M
  if (i >= N_NODES * 64) return;
  int c0 = (i & 63) * 2;
  const float inv = 1.f / (float)N_NODES;
  unsigned int v = h[i];
  float a = __uint_as_float(v << 16);
  float b = __uint_as_float(v & 0xffff0000u);
  float ma = sums[c0] * inv;
  float va = sums[128 + c0] * inv - ma * ma;
  float xa = fmaxf((a - ma) * rsqrtf(va + 1e-5f) * gamma[c0] + beta[c0], 0.f);
  float mb = sums[c0 + 1] * inv;
  float vb = sums[128 + c0 + 1] * inv - mb * mb;
  float xb = fmaxf((b - mb) * rsqrtf(vb + 1e-5f) * gamma[c0 + 1] + beta[c0 + 1], 0.f);
  h[i] = (unsigned int)f2bf(xa) | ((unsigned int)f2bf(xb) << 16);
}

// ---------------- launcher ----------------
extern "C" void kernel_launch(void* const* d_in, const int* in_sizes, int n_in,
                              void* d_out, int out_size, void* d_ws, size_t ws_size,
                              hipStream_t stream) {
  (void)in_sizes; (void)n_in; (void)out_size; (void)ws_size;
  const float* x     = (const float*)d_in[0];
  const int*   eidx  = (const int*)d_in[1];
  const float* W_l1  = (const float*)d_in[2];
  const float* b_l1  = (const float*)d_in[3];
  const float* W_r1  = (const float*)d_in[4];
  const float* gamma = (const float*)d_in[5];
  const float* beta  = (const float*)d_in[6];
  const float* W_l2  = (const float*)d_in[7];
  const float* b_l2  = (const float*)d_in[8];
  const float* W_r2  = (const float*)d_in[9];
  const int* srcp = eidx;
  const int* dstp = eidx + N_EDGES;
  float* out = (float*)d_out;

  // workspace layout (4-byte words; all sections 16B aligned)
  int* wsi = (int*)d_ws;
  int*   counts    = wsi;                         // 50000
  float* sums      = (float*)(wsi + 50000);       // 256
  int*   row_ptr   = wsi + 50304;                 // 50001
  int*   cursor    = wsi + 100308;                // 50000
  int*   elist     = wsi + 150308;                // 800000
  int*   blocksums = wsi + 950308;                // 196 (+pad to 950512)
  unsigned int* x_bf   = (unsigned int*)(wsi + 950512);    // 3.2M words
  unsigned int* agg_bf = (unsigned int*)(wsi + 4150512);   // 3.2M words
  unsigned int* h_bf   = (unsigned int*)(wsi + 7350512);   // 3.2M words
  unsigned short* Wcat1 = (unsigned short*)(wsi + 10550512); // 16384 words
  unsigned short* Wcat2 = (unsigned short*)(wsi + 10566896); // 4096 words
  // total ~= 42.3 MiB

  hipMemsetAsync(d_ws, 0, (size_t)50256 * 4, stream);  // counts + bn sums

  hist_kernel<<<dim3((N_EDGES + 255) / 256), 256, 0, stream>>>(dstp, counts);
  block_sum_kernel<<<dim3(NBLK_SCAN), 256, 0, stream>>>(counts, blocksums);
  scan_fill_kernel<<<dim3(NBLK_SCAN), 256, 0, stream>>>(counts, blocksums, row_ptr, cursor);
  fill_kernel<<<dim3((N_EDGES + 255) / 256), 256, 0, stream>>>(srcp, dstp, cursor, elist);

  to_bf16_kernel<<<dim3(6250), 256, 0, stream>>>(x, x_bf, N_NODES * DH / 4);
  convert_weights<<<dim3(160), 256, 0, stream>>>(W_l1, W_r1, W_l2, W_r2, Wcat1, Wcat2);

  // layer 1
  agg_max_bf16<<<dim3(N_NODES / 4), 256, 0, stream>>>(x_bf, row_ptr, elist, agg_bf);
  gemm_mfma<8, true><<<dim3(391), 256, 0, stream>>>(
      (const unsigned short*)agg_bf, (const unsigned short*)x_bf, Wcat1, b_l1,
      (unsigned short*)h_bf, nullptr, N_NODES);
  bn_stats_kernel<<<dim3(500), 256, 0, stream>>>(h_bf, sums);
  bn_apply_kernel<<<dim3(12500), 256, 0, stream>>>(h_bf, sums, gamma, beta);

  // layer 2
  agg_max_bf16<<<dim3(N_NODES / 4), 256, 0, stream>>>(h_bf, row_ptr, elist, agg_bf);
  gemm_mfma<2, false><<<dim3(391), 256, 0, stream>>>(
      (const unsigned short*)agg_bf, (const unsigned short*)h_bf, Wcat2, b_l2,
      nullptr, out, N_NODES);
}

// Round 4
// 333.995 us; speedup vs baseline: 1.8407x; 1.2528x over previous
//
#include <hip/hip_runtime.h>
#include <math.h>
#include <float.h>

#define N_NODES 50000
#define N_EDGES 800000
#define DH 128
#define NBLK_SCAN 196  // 196*256 = 50176 >= 50001

typedef __attribute__((ext_vector_type(8))) short bf16x8;
typedef __attribute__((ext_vector_type(4))) float f32x4;

static __device__ __forceinline__ unsigned short f2bf(float f) {
  unsigned int u = __float_as_uint(f);
  u = (u + 0x7fff + ((u >> 16) & 1)) >> 16;  // RNE
  return (unsigned short)u;
}

// ---------------- CSR build ----------------
__global__ void hist_kernel(const int* __restrict__ dst, int* __restrict__ counts) {
  int e = blockIdx.x * 256 + threadIdx.x;
  if (e < N_EDGES) atomicAdd(&counts[dst[e]], 1);
}

__global__ __launch_bounds__(256) void block_sum_kernel(const int* __restrict__ counts,
                                                        int* __restrict__ blocksums) {
  int t = threadIdx.x;
  int idx = blockIdx.x * 256 + t;
  int v = (idx < N_NODES) ? counts[idx] : 0;
  __shared__ int s[256];
  s[t] = v;
  __syncthreads();
  for (int off = 128; off > 0; off >>= 1) {
    if (t < off) s[t] += s[t + off];
    __syncthreads();
  }
  if (t == 0) blocksums[blockIdx.x] = s[0];
}

__global__ __launch_bounds__(256) void scan_fill_kernel(const int* __restrict__ counts,
                                                        const int* __restrict__ blocksums,
                                                        int* __restrict__ row_ptr,
                                                        int* __restrict__ cursor) {
  __shared__ int s[256];
  int t = threadIdx.x;
  s[t] = (t < NBLK_SCAN) ? blocksums[t] : 0;
  __syncthreads();
  for (int off = 1; off < 256; off <<= 1) {
    int v = (t >= off) ? s[t - off] : 0;
    __syncthreads();
    s[t] += v;
    __syncthreads();
  }
  int base = (blockIdx.x == 0) ? 0 : s[blockIdx.x - 1];
  __syncthreads();
  int idx = blockIdx.x * 256 + t;
  int c = (idx < N_NODES) ? counts[idx] : 0;
  s[t] = c;
  __syncthreads();
  for (int off = 1; off < 256; off <<= 1) {
    int v = (t >= off) ? s[t - off] : 0;
    __syncthreads();
    s[t] += v;
    __syncthreads();
  }
  int rp = base + s[t] - c;
  if (idx < N_NODES) { row_ptr[idx] = rp; cursor[idx] = rp; }
  if (idx == N_NODES) row_ptr[N_NODES] = rp;
}

__global__ void fill_kernel(const int* __restrict__ src, const int* __restrict__ dst,
                            int* __restrict__ cursor, int* __restrict__ elist) {
  int e = blockIdx.x * 256 + threadIdx.x;
  if (e < N_EDGES) {
    int p = atomicAdd(&cursor[dst[e]], 1);
    elist[p] = src[e];
  }
}

// ---------------- conversions ----------------
__global__ __launch_bounds__(256) void to_bf16_kernel(const float* __restrict__ in,
                                                      unsigned int* __restrict__ out, int n4) {
  int i = blockIdx.x * 256 + threadIdx.x;
  if (i >= n4) return;
  float4 v = ((const float4*)in)[i];
  uint2 o;
  o.x = (unsigned int)f2bf(v.x) | ((unsigned int)f2bf(v.y) << 16);
  o.y = (unsigned int)f2bf(v.z) | ((unsigned int)f2bf(v.w) << 16);
  ((uint2*)out)[i] = o;
}

// Wcat1[128][256] = [Wl1 | Wr1] rows; Wcat2[32][256] = [Wl2 | Wr2] rows (bf16)
__global__ __launch_bounds__(256) void convert_weights(
    const float* __restrict__ Wl1, const float* __restrict__ Wr1,
    const float* __restrict__ Wl2, const float* __restrict__ Wr2,
    unsigned short* __restrict__ Wcat1, unsigned short* __restrict__ Wcat2) {
  int i = blockIdx.x * 256 + threadIdx.x;  // 160*256 = 40960 total
  if (i < 32768) {
    int n = i >> 8, k = i & 255;
    float w = (k < 128) ? Wl1[n * 128 + k] : Wr1[n * 128 + (k - 128)];
    Wcat1[i] = f2bf(w);
  } else if (i < 40960) {
    int j = i - 32768;
    int n = j >> 8, k = j & 255;
    float w = (k < 128) ? Wl2[n * 128 + k] : Wr2[n * 128 + (k - 128)];
    Wcat2[j] = f2bf(w);
  }
}

// ---------------- CSR gather-max, 4 edge-slots x 16 lanes, unroll x2 ----------------
// Wave per node. eslot = lane>>4 handles edges base+eslot (+4); fq = lane&15 loads
// uint4 (8 bf16) of the row. 8 independent dwordx4 gathers in flight per iteration.
// Tail edges clamp to last edge: re-maxing a duplicate is idempotent.
__global__ __launch_bounds__(256) void agg_max_bf16(const uint4* __restrict__ feat4,
                                                    const int* __restrict__ row_ptr,
                                                    const int* __restrict__ elist,
                                                    uint4* __restrict__ out4) {
  int node = blockIdx.x * 4 + (threadIdx.x >> 6);
  int lane = threadIdx.x & 63;
  int eslot = lane >> 4;
  int fq = lane & 15;
  int e0 = row_ptr[node];
  int e1 = row_ptr[node + 1];
  float m[8];
#pragma unroll
  for (int j = 0; j < 8; ++j) m[j] = -FLT_MAX;

  if (e0 < e1) {
    const int last = e1 - 1;
    for (int base = e0; base < e1; base += 8) {
      int ea = base + eslot;     if (ea > last) ea = last;
      int eb = base + 4 + eslot; if (eb > last) eb = last;
      int sa = elist[ea];
      int sb = elist[eb];
      uint4 va = feat4[(size_t)sa * 16 + fq];
      uint4 vb = feat4[(size_t)sb * 16 + fq];
      const unsigned int* pa = (const unsigned int*)&va;
      const unsigned int* pb = (const unsigned int*)&vb;
#pragma unroll
      for (int c = 0; c < 4; ++c) {
        m[2 * c]     = fmaxf(m[2 * c],     fmaxf(__uint_as_float(pa[c] << 16),
                                                 __uint_as_float(pb[c] << 16)));
        m[2 * c + 1] = fmaxf(m[2 * c + 1], fmaxf(__uint_as_float(pa[c] & 0xffff0000u),
                                                 __uint_as_float(pb[c] & 0xffff0000u)));
      }
    }
  }

  // reduce across the 4 edge-slots (lanes differing in bits 4,5)
#pragma unroll
  for (int j = 0; j < 8; ++j) {
    m[j] = fmaxf(m[j], __shfl_xor(m[j], 16, 64));
    m[j] = fmaxf(m[j], __shfl_xor(m[j], 32, 64));
  }
  if (e0 == e1) {
#pragma unroll
    for (int j = 0; j < 8; ++j) m[j] = 0.f;
  }
  if (eslot == 0) {
    uint4 o;  // inputs bf16-exact -> truncation exact
    o.x = (__float_as_uint(m[0]) >> 16) | (__float_as_uint(m[1]) & 0xffff0000u);
    o.y = (__float_as_uint(m[2]) >> 16) | (__float_as_uint(m[3]) & 0xffff0000u);
    o.z = (__float_as_uint(m[4]) >> 16) | (__float_as_uint(m[5]) & 0xffff0000u);
    o.w = (__float_as_uint(m[6]) >> 16) | (__float_as_uint(m[7]) & 0xffff0000u);
    out4[(size_t)node * 16 + fq] = o;
  }
}

// ---------------- MFMA GEMM: out = [Aa|Ab](bf16) @ Wcat^T + bias ----------------
#define ASTR 264  // 256+8 bf16 pad: dword row stride 132 % 32 = 4 -> 2-way (free)

template <int NT, bool BF16OUT>
__global__ __launch_bounds__(256) void gemm_mfma(
    const unsigned short* __restrict__ Aa, const unsigned short* __restrict__ Ab,
    const unsigned short* __restrict__ Wcat, const float* __restrict__ bias,
    unsigned short* __restrict__ outb, float* __restrict__ outf, int N) {
  __shared__ unsigned short Alds[128 * ASTR];  // 67.6 KB
  const int tid = threadIdx.x;
  const int rowBase = blockIdx.x * 128;

#pragma unroll
  for (int it = 0; it < 16; ++it) {
    int f = tid + it * 256;        // 0..4095
    int r = f >> 5;
    int seg = f & 31;              // 32 x 16B per row
    int n = rowBase + r;
    if (n >= N) n = N - 1;
    const unsigned short* src = (seg < 16)
        ? (Aa + (size_t)n * 128 + seg * 8)
        : (Ab + (size_t)n * 128 + (seg - 16) * 8);
    int4 d = *(const int4*)src;
    *(int4*)(&Alds[r * ASTR + seg * 8]) = d;
  }
  __syncthreads();

  const int wv = tid >> 6;
  const int lane = tid & 63;
  const int ln15 = lane & 15;
  const int quad = lane >> 4;
  const int m0 = wv * 32;

  f32x4 acc[2][NT] = {};

#pragma unroll
  for (int ks = 0; ks < 8; ++ks) {
    const int k0 = ks * 32;
    bf16x8 a0 = *(const bf16x8*)(&Alds[(m0 + ln15) * ASTR + k0 + quad * 8]);
    bf16x8 a1 = *(const bf16x8*)(&Alds[(m0 + 16 + ln15) * ASTR + k0 + quad * 8]);
#pragma unroll
    for (int nt = 0; nt < NT; ++nt) {
      bf16x8 b = *(const bf16x8*)(Wcat + (size_t)(nt * 16 + ln15) * 256 + k0 + quad * 8);
      acc[0][nt] = __builtin_amdgcn_mfma_f32_16x16x32_bf16(a0, b, acc[0][nt], 0, 0, 0);
      acc[1][nt] = __builtin_amdgcn_mfma_f32_16x16x32_bf16(a1, b, acc[1][nt], 0, 0, 0);
    }
  }

  const int ldo = NT * 16;
#pragma unroll
  for (int mt = 0; mt < 2; ++mt) {
#pragma unroll
    for (int nt = 0; nt < NT; ++nt) {
      int col = nt * 16 + ln15;
      float bv = bias[col];
#pragma unroll
      for (int i = 0; i < 4; ++i) {
        int r = rowBase + m0 + mt * 16 + quad * 4 + i;
        if (r < N) {
          float val = acc[mt][nt][i] + bv;
          if (BF16OUT)
            outb[(size_t)r * ldo + col] = f2bf(val);
          else
            outf[(size_t)r * ldo + col] = val;
        }
      }
    }
  }
}

// ---------------- batch-norm on packed bf16 h ----------------
__global__ __launch_bounds__(256) void bn_stats_kernel(const unsigned int* __restrict__ h,
                                                       float* __restrict__ sums) {
  int j2 = threadIdx.x & 63;
  int rg = threadIdx.x >> 6;
  float sa = 0.f, qa = 0.f, sb = 0.f, qb = 0.f;
  for (int n = blockIdx.x * 4 + rg; n < N_NODES; n += gridDim.x * 4) {
    unsigned int v = h[(size_t)n * 64 + j2];
    float a = __uint_as_float(v << 16);
    float b = __uint_as_float(v & 0xffff0000u);
    sa += a; qa += a * a; sb += b; qb += b * b;
  }
  __shared__ float r0[256], r1[256], r2[256], r3[256];
  r0[threadIdx.x] = sa; r1[threadIdx.x] = qa;
  r2[threadIdx.x] = sb; r3[threadIdx.x] = qb;
  __syncthreads();
  if (threadIdx.x < 64) {
    int t = threadIdx.x;
    float SA = r0[t] + r0[t + 64] + r0[t + 128] + r0[t + 192];
    float QA = r1[t] + r1[t + 64] + r1[t + 128] + r1[t + 192];
    float SB = r2[t] + r2[t + 64] + r2[t + 128] + r2[t + 192];
    float QB = r3[t] + r3[t + 64] + r3[t + 128] + r3[t + 192];
    atomicAdd(&sums[2 * t], SA);
    atomicAdd(&sums[2 * t + 1], SB);
    atomicAdd(&sums[128 + 2 * t], QA);
    atomicAdd(&sums[128 + 2 * t + 1], QB);
  }
}

__global__ __launch_bounds__(256) void bn_apply_kernel(unsigned int* __restrict__ h,
                                                       const float* __restrict__ sums,
                                                       const float* __restrict__ gamma,
                                                       const float* __restrict__ beta) {
  int i = blockIdx.x * 256 + threadIdx.x;
  if (i >= N_NODES * 64) return;
  int c0 = (i & 63) * 2;
  const float inv = 1.f / (float)N_NODES;
  unsigned int v = h[i];
  float a = __uint_as_float(v << 16);
  float b = __uint_as_float(v & 0xffff0000u);
  float ma = sums[c0] * inv;
  float va = sums[128 + c0] * inv - ma * ma;
  float xa = fmaxf((a - ma) * rsqrtf(va + 1e-5f) * gamma[c0] + beta[c0], 0.f);
  float mb = sums[c0 + 1] * inv;
  float vb = sums[128 + c0 + 1] * inv - mb * mb;
  float xb = fmaxf((b - mb) * rsqrtf(vb + 1e-5f) * gamma[c0 + 1] + beta[c0 + 1], 0.f);
  h[i] = (unsigned int)f2bf(xa) | ((unsigned int)f2bf(xb) << 16);
}

// ---------------- launcher ----------------
extern "C" void kernel_launch(void* const* d_in, const int* in_sizes, int n_in,
                              void* d_out, int out_size, void* d_ws, size_t ws_size,
                              hipStream_t stream) {
  (void)in_sizes; (void)n_in; (void)out_size; (void)ws_size;
  const float* x     = (const float*)d_in[0];
  const int*   eidx  = (const int*)d_in[1];
  const float* W_l1  = (const float*)d_in[2];
  const float* b_l1  = (const float*)d_in[3];
  const float* W_r1  = (const float*)d_in[4];
  const float* gamma = (const float*)d_in[5];
  const float* beta  = (const float*)d_in[6];
  const float* W_l2  = (const float*)d_in[7];
  const float* b_l2  = (const float*)d_in[8];
  const float* W_r2  = (const float*)d_in[9];
  const int* srcp = eidx;
  const int* dstp = eidx + N_EDGES;
  float* out = (float*)d_out;

  int* wsi = (int*)d_ws;
  int*   counts    = wsi;                         // 50000
  float* sums      = (float*)(wsi + 50000);       // 256
  int*   row_ptr   = wsi + 50304;                 // 50001
  int*   cursor    = wsi + 100308;                // 50000
  int*   elist     = wsi + 150308;                // 800000
  int*   blocksums = wsi + 950308;                // 196 (+pad to 950512)
  unsigned int* x_bf   = (unsigned int*)(wsi + 950512);    // 3.2M words
  unsigned int* agg_bf = (unsigned int*)(wsi + 4150512);   // 3.2M words
  unsigned int* h_bf   = (unsigned int*)(wsi + 7350512);   // 3.2M words
  unsigned short* Wcat1 = (unsigned short*)(wsi + 10550512); // 16384 words
  unsigned short* Wcat2 = (unsigned short*)(wsi + 10566896); // 4096 words

  hipMemsetAsync(d_ws, 0, (size_t)50256 * 4, stream);  // counts + bn sums

  hist_kernel<<<dim3((N_EDGES + 255) / 256), 256, 0, stream>>>(dstp, counts);
  block_sum_kernel<<<dim3(NBLK_SCAN), 256, 0, stream>>>(counts, blocksums);
  scan_fill_kernel<<<dim3(NBLK_SCAN), 256, 0, stream>>>(counts, blocksums, row_ptr, cursor);
  fill_kernel<<<dim3((N_EDGES + 255) / 256), 256, 0, stream>>>(srcp, dstp, cursor, elist);

  to_bf16_kernel<<<dim3(6250), 256, 0, stream>>>(x, x_bf, N_NODES * DH / 4);
  convert_weights<<<dim3(160), 256, 0, stream>>>(W_l1, W_r1, W_l2, W_r2, Wcat1, Wcat2);

  // layer 1
  agg_max_bf16<<<dim3(N_NODES / 4), 256, 0, stream>>>(
      (const uint4*)x_bf, row_ptr, elist, (uint4*)agg_bf);
  gemm_mfma<8, true><<<dim3(391), 256, 0, stream>>>(
      (const unsigned short*)agg_bf, (const unsigned short*)x_bf, Wcat1, b_l1,
      (unsigned short*)h_bf, nullptr, N_NODES);
  bn_stats_kernel<<<dim3(500), 256, 0, stream>>>(h_bf, sums);
  bn_apply_kernel<<<dim3(12500), 256, 0, stream>>>(h_bf, sums, gamma, beta);

  // layer 2
  agg_max_bf16<<<dim3(N_NODES / 4), 256, 0, stream>>>(
      (const uint4*)h_bf, row_ptr, elist, (uint4*)agg_bf);
  gemm_mfma<2, false><<<dim3(391), 256, 0, stream>>>(
      (const unsigned short*)agg_bf, (const unsigned short*)h_bf, Wcat2, b_l2,
      nullptr, out, N_NODES);
}